// Round 8
// baseline (337.550 us; speedup 1.0000x reference)
//
#include <hip/hip_runtime.h>
#include <math.h>

// Problem: P=2, S=2, C=64, F=64, B=64
//   scores[p,s,c,d] = sum_{f,f2} dbfc[p,s,c,f,d,f2]      (268 MB streaming reduction)
//   weights = softmax(scores, axis=d)
//   v[b,ps,d,f1] = sum_f0 X[b,ps,d,f0] * wV[f1,f0]
//   out[c, b, ps*64+f1] = sum_d weights[ps,c,d] * v[b,ps,d,f1]
//
// FUSED single kernel: 2048 blocks (whole grid resident at 8 blocks/CU).
// All blocks run the round-4 A body (best measured: ~5.85 TB/s).
// Blocks with chunk==7 continue as B-role for (ps,b)=slab: X-stage + phase-1
// v overlap the A stream; a device-scope counter (release-add / acquire-spin)
// gates the softmax+phase-2 epilogue. LDS 18.4 KB keeps 8 blocks/CU.

typedef float floatx4 __attribute__((ext_vector_type(4)));

#define TOTAL_BLOCKS 2048u

__global__ __launch_bounds__(256, 8) void fused_attn_kernel(
    const float* __restrict__ X, const float* __restrict__ dbfc,
    const float* __restrict__ wV, float* __restrict__ partials,
    unsigned int* __restrict__ counter, float* __restrict__ out)
{
    const int bid   = blockIdx.x;         // 0..2047
    const int slab  = bid >> 3;           // (ps*64 + c)  /  B-role: (ps*64 + b)
    const int chunk = bid & 7;
    const int t     = threadIdx.x;        // 0..255

    // 18432 B arena: phase-1 X-stage [64][68]=4352 fl; then Ws[64][36]+VsT[64][36]
    __shared__ __align__(16) float arena[4608];

    // ===== stage 1: A body (byte-identical math to round 4) =====
    {
        const floatx4* src = reinterpret_cast<const floatx4*>(dbfc)
                           + (size_t)slab * 65536 + chunk * 8192 + t;
        floatx4 a0 = (floatx4)0.f, a1 = (floatx4)0.f, a2 = (floatx4)0.f, a3 = (floatx4)0.f;
#pragma unroll 2
        for (int i = 0; i < 32; i += 4) {
            floatx4 v0 = __builtin_nontemporal_load(&src[(i + 0) * 256]);
            floatx4 v1 = __builtin_nontemporal_load(&src[(i + 1) * 256]);
            floatx4 v2 = __builtin_nontemporal_load(&src[(i + 2) * 256]);
            floatx4 v3 = __builtin_nontemporal_load(&src[(i + 3) * 256]);
            a0 += v0; a1 += v1; a2 += v2; a3 += v3;
        }
        float s0 = (a0.x + a0.y) + (a0.z + a0.w);
        float s1 = (a1.x + a1.y) + (a1.z + a1.w);
        float s2 = (a2.x + a2.y) + (a2.z + a2.w);
        float s3 = (a3.x + a3.y) + (a3.z + a3.w);
#pragma unroll
        for (int m = 1; m < 16; m <<= 1) {
            s0 += __shfl_xor(s0, m, 64);
            s1 += __shfl_xor(s1, m, 64);
            s2 += __shfl_xor(s2, m, 64);
            s3 += __shfl_xor(s3, m, 64);
        }
        if ((t & 15) == 0) {
            float* dst = partials + (size_t)chunk * 16384 + slab * 64 + (t >> 4);
            dst[ 0] = s0; dst[16] = s1; dst[32] = s2; dst[48] = s3;
        }
    }
    // barrier drains every wave's stores (compiler emits vmcnt(0) before
    // s_barrier), so t0's release-add covers the whole block's partials.
    __syncthreads();
    if (t == 0)
        __hip_atomic_fetch_add(counter, 1u, __ATOMIC_RELEASE,
                               __HIP_MEMORY_SCOPE_AGENT);
    if (chunk != 7) return;

    // ===== B role: (ps, b) =====
    const int ps = slab >> 6;
    const int b  = slab & 63;
    const int tc = t >> 4;            // 0..15
    const int tf = t & 15;            // 0..15

    // stage X slab into arena[64][68] (stride-68 rows: round-4 pattern)
    const float4* xsrc = reinterpret_cast<const float4*>(X + (size_t)b * 16384 + ps * 4096);
#pragma unroll
    for (int idx = t; idx < 1024; idx += 256) {
        int r = idx >> 4, j = (idx & 15) * 4;
        *reinterpret_cast<float4*>(&arena[r * 68 + j]) = xsrc[idx];
    }
    __syncthreads();

    // phase 1 — v: acc[ci][fi] = sum_f0 X[4tc+ci][f0] * wV[tf+16fi][f0]
    // (wV rows straight from global: 16 KB, L1-resident, 16x lane reuse)
    float acc[4][4] = {};
    const float4* wvg = reinterpret_cast<const float4*>(wV);
    for (int f0 = 0; f0 < 64; f0 += 4) {
        float4 xa[4], wv[4];
#pragma unroll
        for (int ci = 0; ci < 4; ++ci)
            xa[ci] = *reinterpret_cast<const float4*>(&arena[(4 * tc + ci) * 68 + f0]);
#pragma unroll
        for (int fi = 0; fi < 4; ++fi)
            wv[fi] = wvg[(tf + 16 * fi) * 16 + (f0 >> 2)];
#pragma unroll
        for (int ci = 0; ci < 4; ++ci)
#pragma unroll
            for (int fi = 0; fi < 4; ++fi)
                acc[ci][fi] += xa[ci].x * wv[fi].x + xa[ci].y * wv[fi].y
                             + xa[ci].z * wv[fi].z + xa[ci].w * wv[fi].w;
    }

    // wait until every block has published its partials (acquire invalidates
    // stale L1/L2 lines; whole grid is resident so no dispatch starvation)
    if (t == 0) {
        while (__hip_atomic_load(counter, __ATOMIC_ACQUIRE,
                                 __HIP_MEMORY_SCOPE_AGENT) < TOTAL_BLOCKS)
            __builtin_amdgcn_s_sleep(8);
    }
    __syncthreads();

    // softmax: row = t>>2 (0..63), quarter q = (t&3)*16; weights stay in regs
    const int row = t >> 2, q = (t & 3) * 16;
    float w16[16];
    {
        const float4* psrc = reinterpret_cast<const float4*>(partials);
        float4 p0 = make_float4(0.f, 0.f, 0.f, 0.f), p1 = p0, p2 = p0, p3 = p0;
#pragma unroll
        for (int k = 0; k < 8; ++k) {
            const float4* prow = &psrc[k * 4096 + (ps * 64 + row) * 16 + (t & 3) * 4];
            float4 u0 = prow[0], u1 = prow[1], u2 = prow[2], u3 = prow[3];
            p0.x += u0.x; p0.y += u0.y; p0.z += u0.z; p0.w += u0.w;
            p1.x += u1.x; p1.y += u1.y; p1.z += u1.z; p1.w += u1.w;
            p2.x += u2.x; p2.y += u2.y; p2.z += u2.z; p2.w += u2.w;
            p3.x += u3.x; p3.y += u3.y; p3.z += u3.z; p3.w += u3.w;
        }
        float e[16] = { p0.x, p0.y, p0.z, p0.w,  p1.x, p1.y, p1.z, p1.w,
                        p2.x, p2.y, p2.z, p2.w,  p3.x, p3.y, p3.z, p3.w };
        float mx = -INFINITY;
#pragma unroll
        for (int i = 0; i < 16; ++i) mx = fmaxf(mx, e[i]);
        mx = fmaxf(mx, __shfl_xor(mx, 1, 64));
        mx = fmaxf(mx, __shfl_xor(mx, 2, 64));
        float sum = 0.f;
#pragma unroll
        for (int i = 0; i < 16; ++i) { e[i] = expf(e[i] - mx); sum += e[i]; }
        sum += __shfl_xor(sum, 1, 64);
        sum += __shfl_xor(sum, 2, 64);
        const float rinv = 1.0f / sum;
#pragma unroll
        for (int i = 0; i < 16; ++i) w16[i] = e[i] * rinv;
    }

    // phase 2 over d-halves; arena reused: Ws[64][36] + VsT[64][36]
    float* Wh = arena;           // [64][36]
    float* Vh = arena + 2304;    // [64][36]
    float o[4][4] = {};
#pragma unroll
    for (int dh = 0; dh < 2; ++dh) {
        __syncthreads();     // X-stage (dh=0) / previous half (dh=1) consumed
        if (((t & 3) >> 1) == dh) {
#pragma unroll
            for (int i = 0; i < 16; ++i)
                Wh[row * 36 + (q & 31) + i] = w16[i];
        }
        if ((tc >> 3) == dh) {
#pragma unroll
            for (int ci = 0; ci < 4; ++ci)
#pragma unroll
                for (int fi = 0; fi < 4; ++fi)
                    Vh[(tf + 16 * fi) * 36 + ((4 * tc + ci) & 31)] = acc[ci][fi];
        }
        __syncthreads();
        for (int d4 = 0; d4 < 32; d4 += 4) {
            float4 wa[4], va[4];
#pragma unroll
            for (int ci = 0; ci < 4; ++ci)
                wa[ci] = *reinterpret_cast<const float4*>(&Wh[(4 * tc + ci) * 36 + d4]);
#pragma unroll
            for (int fi = 0; fi < 4; ++fi)
                va[fi] = *reinterpret_cast<const float4*>(&Vh[(tf + 16 * fi) * 36 + d4]);
#pragma unroll
            for (int ci = 0; ci < 4; ++ci)
#pragma unroll
                for (int fi = 0; fi < 4; ++fi)
                    o[ci][fi] += wa[ci].x * va[fi].x + wa[ci].y * va[fi].y
                               + wa[ci].z * va[fi].z + wa[ci].w * va[fi].w;
        }
    }

    // out[c, b, ps*64 + f1],  c = 4tc+ci,  f1 = tf+16fi
#pragma unroll
    for (int ci = 0; ci < 4; ++ci) {
        const int c = 4 * tc + ci;
        float* orow = out + ((size_t)c * 64 + b) * 256 + ps * 64;
#pragma unroll
        for (int fi = 0; fi < 4; ++fi)
            orow[tf + 16 * fi] = o[ci][fi];
    }
}

extern "C" void kernel_launch(void* const* d_in, const int* in_sizes, int n_in,
                              void* d_out, int out_size, void* d_ws, size_t ws_size,
                              hipStream_t stream)
{
    const float* X    = (const float*)d_in[0];  // [64, 16384]
    const float* dbfc = (const float*)d_in[1];  // [2,2,64,64,64,64]
    const float* wV   = (const float*)d_in[2];  // [64, 64]
    float* out        = (float*)d_out;          // [64, 64, 256]
    float* partials   = (float*)d_ws;           // [8][256][64] = 512 KB
    unsigned int* counter =
        (unsigned int*)((char*)d_ws + 8u * 256u * 64u * sizeof(float));

    hipMemsetAsync(counter, 0, sizeof(unsigned int), stream);
    fused_attn_kernel<<<TOTAL_BLOCKS, 256, 0, stream>>>(X, dbfc, wV, partials,
                                                        counter, out);
}

// Round 9
// 59.840 us; speedup vs baseline: 5.6409x; 5.6409x over previous
//
#include <hip/hip_runtime.h>
#include <math.h>

// Problem: P=2, S=2, C=64, F=64, B=64
//   scores[p,s,c,d] = sum_{f,f2} dbfc[p,s,c,f,d,f2]      (268 MB streaming reduction)
//   weights = softmax(scores, axis=d)                     (fused into kernel B prologue)
//   v[b,ps,c,f1] = sum_f0 X[b,ps,c,f0] * wV[f1,f0]
//   out[c, b, ps*64+f1] = sum_d weights[ps,c,d] * v[b,ps,d,f1]

// clang native vector type — __builtin_nontemporal_load requires this
// (HIP_vector_type float4 is a struct and is rejected).
typedef float floatx4 __attribute__((ext_vector_type(4)));

// ---------------------------------------------------------------------------
// Kernel A: 2048 blocks x 256 threads (8 blocks/CU, 32 waves/CU — round-4
// occupancy held). ONE variable vs round 4: 32 B/lane (2 consecutive float4)
// per issue -> 2 KB contiguous per wave-issue-pair (vs 1 KB), testing the
// last unmeasured cell of {granularity x occupancy}. Block still owns the
// same contiguous 128 KB chunk. d-mapping: float4 j = i*512 + 2t ->
// d = (t>>3) + 32*(i&1): even/odd-i accumulator pairs, 8-lane shfl reduce,
// 32 writer lanes store d and d+32. Same FP tree depth as round 4.
// ---------------------------------------------------------------------------
__global__ __launch_bounds__(256) void scores_partial_kernel(
    const float* __restrict__ dbfc, float* __restrict__ partials)
{
    const int bid   = blockIdx.x;         // 0..2047
    const int slab  = bid >> 3;           // (ps*64 + c)
    const int chunk = bid & 7;
    const int t     = threadIdx.x;        // 0..255

    const floatx4* src = reinterpret_cast<const floatx4*>(dbfc)
                       + (size_t)slab * 65536 + chunk * 8192 + 2 * t;

    floatx4 e0 = (floatx4)0.f, e1 = (floatx4)0.f;   // i even: d = t>>3
    floatx4 o0 = (floatx4)0.f, o1 = (floatx4)0.f;   // i odd : d = (t>>3)+32
#pragma unroll 2
    for (int i = 0; i < 16; i += 2) {
        floatx4 va = __builtin_nontemporal_load(&src[(i + 0) * 512 + 0]);
        floatx4 vb = __builtin_nontemporal_load(&src[(i + 0) * 512 + 1]);
        floatx4 vc = __builtin_nontemporal_load(&src[(i + 1) * 512 + 0]);
        floatx4 vd = __builtin_nontemporal_load(&src[(i + 1) * 512 + 1]);
        e0 += va; e1 += vb;
        o0 += vc; o1 += vd;
    }
    floatx4 es = e0 + e1, os = o0 + o1;
    float se = (es.x + es.y) + (es.z + es.w);
    float so = (os.x + os.y) + (os.z + os.w);
    // reduce across the 8 lanes sharing d0 = t>>3 (groups never cross waves)
#pragma unroll
    for (int m = 1; m < 8; m <<= 1) {
        se += __shfl_xor(se, m, 64);
        so += __shfl_xor(so, m, 64);
    }
    if ((t & 7) == 0) {
        float* dst = partials + (size_t)chunk * 16384 + slab * 64 + (t >> 3);
        dst[ 0] = se;
        dst[32] = so;
    }
}

// ---------------------------------------------------------------------------
// Kernel B — byte-identical to round 4 (proven best): one block per (ps, b).
// Stages X-slab / wV in LDS, reduces the 8 score partials into Ws while
// staging, softmaxes the 64 rows (4 thr/row), computes v with 4x4 register
// tiles, transposes via LDS, then weights @ v. Stride-68 rows: conflict-free.
// ---------------------------------------------------------------------------
__global__ __launch_bounds__(256) void attn_out_kernel(
    const float* __restrict__ X, const float* __restrict__ wV,
    const float* __restrict__ partials, float* __restrict__ out)
{
    const int blk = blockIdx.x;   // 0..255
    const int ps  = blk >> 6;     // 0..3
    const int b   = blk & 63;     // 0..63
    const int t   = threadIdx.x;  // 0..255
    const int tc  = t >> 4;       // 0..15
    const int tf  = t & 15;       // 0..15

    __shared__ float Xs [64][68];   // X[b, ps, c, f0]
    __shared__ float wVs[64][68];   // wV[f1][f0]
    __shared__ float Ws [64][68];   // summed scores -> softmaxed weights [c][d]
    __shared__ float VsT[64][68];   // v transposed: [f1][c]

    const float4* xsrc = reinterpret_cast<const float4*>(X + (size_t)b * 16384 + ps * 4096);
    const float4* wsrc = reinterpret_cast<const float4*>(wV);
    const float4* psrc = reinterpret_cast<const float4*>(partials);
#pragma unroll
    for (int idx = t; idx < 1024; idx += 256) {
        int r = idx >> 4, jq = idx & 15, j = jq * 4;
        *reinterpret_cast<float4*>(&Xs [r][j]) = xsrc[idx];
        *reinterpret_cast<float4*>(&wVs[r][j]) = wsrc[idx];
        // sum the 8 chunk partials for (c=r, d=j..j+3)
        float4 s = make_float4(0.f, 0.f, 0.f, 0.f);
#pragma unroll
        for (int k = 0; k < 8; ++k) {
            float4 p = psrc[k * 4096 + (ps * 64 + r) * 16 + jq];
            s.x += p.x; s.y += p.y; s.z += p.z; s.w += p.w;
        }
        *reinterpret_cast<float4*>(&Ws [r][j]) = s;
    }
    __syncthreads();

    // v: acc[ci][fi] = sum_f0 Xs[4tc+ci][f0] * wVs[tf+16fi][f0]
    float acc[4][4] = {};
    for (int f0 = 0; f0 < 64; f0 += 4) {
        float4 xa[4], wv[4];
#pragma unroll
        for (int ci = 0; ci < 4; ++ci)
            xa[ci] = *reinterpret_cast<const float4*>(&Xs[4 * tc + ci][f0]);
#pragma unroll
        for (int fi = 0; fi < 4; ++fi)
            wv[fi] = *reinterpret_cast<const float4*>(&wVs[tf + 16 * fi][f0]);
#pragma unroll
        for (int ci = 0; ci < 4; ++ci)
#pragma unroll
            for (int fi = 0; fi < 4; ++fi)
                acc[ci][fi] += xa[ci].x * wv[fi].x + xa[ci].y * wv[fi].y
                             + xa[ci].z * wv[fi].z + xa[ci].w * wv[fi].w;
    }

    // softmax over d for each of the 64 rows of Ws; 4 threads per row
    {
        const int row = t >> 2, q = (t & 3) * 16;
        float e[16];
        float mx = -INFINITY;
#pragma unroll
        for (int i = 0; i < 16; ++i) mx = fmaxf(mx, Ws[row][q + i]);
        mx = fmaxf(mx, __shfl_xor(mx, 1, 64));
        mx = fmaxf(mx, __shfl_xor(mx, 2, 64));
        float sum = 0.f;
#pragma unroll
        for (int i = 0; i < 16; ++i) { e[i] = expf(Ws[row][q + i] - mx); sum += e[i]; }
        sum += __shfl_xor(sum, 1, 64);
        sum += __shfl_xor(sum, 2, 64);
        const float rinv = 1.0f / sum;
#pragma unroll
        for (int i = 0; i < 16; ++i) Ws[row][q + i] = e[i] * rinv;
    }

    // v -> LDS transposed
#pragma unroll
    for (int ci = 0; ci < 4; ++ci)
#pragma unroll
        for (int fi = 0; fi < 4; ++fi)
            VsT[tf + 16 * fi][4 * tc + ci] = acc[ci][fi];
    __syncthreads();

    // out: o[ci][fi] = sum_d Ws[4tc+ci][d] * VsT[tf+16fi][d]
    float o[4][4] = {};
    for (int d = 0; d < 64; d += 4) {
        float4 wa[4], va[4];
#pragma unroll
        for (int ci = 0; ci < 4; ++ci)
            wa[ci] = *reinterpret_cast<const float4*>(&Ws[4 * tc + ci][d]);
#pragma unroll
        for (int fi = 0; fi < 4; ++fi)
            va[fi] = *reinterpret_cast<const float4*>(&VsT[tf + 16 * fi][d]);
#pragma unroll
        for (int ci = 0; ci < 4; ++ci)
#pragma unroll
            for (int fi = 0; fi < 4; ++fi)
                o[ci][fi] += wa[ci].x * va[fi].x + wa[ci].y * va[fi].y
                           + wa[ci].z * va[fi].z + wa[ci].w * va[fi].w;
    }

    // out[c, b, ps*64 + f1],  c = 4tc+ci,  f1 = tf+16fi
#pragma unroll
    for (int ci = 0; ci < 4; ++ci) {
        const int c = 4 * tc + ci;
        float* orow = out + ((size_t)c * 64 + b) * 256 + ps * 64;
#pragma unroll
        for (int fi = 0; fi < 4; ++fi)
            orow[tf + 16 * fi] = o[ci][fi];
    }
}

extern "C" void kernel_launch(void* const* d_in, const int* in_sizes, int n_in,
                              void* d_out, int out_size, void* d_ws, size_t ws_size,
                              hipStream_t stream)
{
    const float* X    = (const float*)d_in[0];  // [64, 16384]
    const float* dbfc = (const float*)d_in[1];  // [2,2,64,64,64,64]
    const float* wV   = (const float*)d_in[2];  // [64, 64]
    float* out        = (float*)d_out;          // [64, 64, 256]
    float* partials   = (float*)d_ws;           // [8][256][64] = 512 KB scratch

    scores_partial_kernel<<<2048, 256, 0, stream>>>(dbfc, partials);
    attn_out_kernel<<<256, 256, 0, stream>>>(X, wV, partials, out);
}

// Round 10
// 54.731 us; speedup vs baseline: 6.1674x; 1.0933x over previous
//
#include <hip/hip_runtime.h>
#include <math.h>

// Problem: P=2, S=2, C=64, F=64, B=64
//   scores[p,s,c,d] = sum_{f,f2} dbfc[p,s,c,f,d,f2]      (268 MB streaming reduction)
//   weights = softmax(scores, axis=d)                     (fused into kernel B prologue)
//   v[b,ps,c,f1] = sum_f0 X[b,ps,c,f0] * wV[f1,f0]
//   out[c, b, ps*64+f1] = sum_d weights[ps,c,d] * v[b,ps,d,f1]
//
// ROUND-4 CONFIGURATION — empirical optimum after a 6-way scan:
//   A: 16 B/lane, 1 KB/wave-issue, 4 KB thread stride, 2048 blocks (32 w/CU),
//      nontemporal loads, partials stores (no atomics/memset)   -> ~5.85 TB/s
//   B: single 256-block kernel, LDS stride-68, fused softmax    -> ~6 µs
// Perturbations measured and rejected: 32B/lane @16w (59.5), 32B/lane @32w
// (59.8), dense-32KB/wave (67.0), 4x-block B (59.9), fused+spin (337).

typedef float floatx4 __attribute__((ext_vector_type(4)));

// ---------------------------------------------------------------------------
// Kernel A: 2048 blocks x 256 threads. Block = 1/8 of a (p,s,c) slab
// (128 KB contiguous = 8 f-values x [d=64][f2=64]). Thread t at iter i reads
// local float4 j = i*256+t -> d = (t>>4) + 16*(i&3): 4 register accumulators.
// Nontemporal loads (pure stream, zero reuse). 16-lane shfl reduce, then
// plain stores of this chunk's 64 partial sums (no atomics, no memset).
// ---------------------------------------------------------------------------
__global__ __launch_bounds__(256) void scores_partial_kernel(
    const float* __restrict__ dbfc, float* __restrict__ partials)
{
    const int bid   = blockIdx.x;         // 0..2047
    const int slab  = bid >> 3;           // (ps*64 + c)
    const int chunk = bid & 7;
    const int t     = threadIdx.x;        // 0..255

    const floatx4* src = reinterpret_cast<const floatx4*>(dbfc)
                       + (size_t)slab * 65536 + chunk * 8192 + t;

    floatx4 a0 = (floatx4)0.f, a1 = (floatx4)0.f, a2 = (floatx4)0.f, a3 = (floatx4)0.f;
#pragma unroll 2
    for (int i = 0; i < 32; i += 4) {
        floatx4 v0 = __builtin_nontemporal_load(&src[(i + 0) * 256]);
        floatx4 v1 = __builtin_nontemporal_load(&src[(i + 1) * 256]);
        floatx4 v2 = __builtin_nontemporal_load(&src[(i + 2) * 256]);
        floatx4 v3 = __builtin_nontemporal_load(&src[(i + 3) * 256]);
        a0 += v0;
        a1 += v1;
        a2 += v2;
        a3 += v3;
    }
    float s0 = (a0.x + a0.y) + (a0.z + a0.w);
    float s1 = (a1.x + a1.y) + (a1.z + a1.w);
    float s2 = (a2.x + a2.y) + (a2.z + a2.w);
    float s3 = (a3.x + a3.y) + (a3.z + a3.w);
#pragma unroll
    for (int m = 1; m < 16; m <<= 1) {
        s0 += __shfl_xor(s0, m, 64);
        s1 += __shfl_xor(s1, m, 64);
        s2 += __shfl_xor(s2, m, 64);
        s3 += __shfl_xor(s3, m, 64);
    }
    if ((t & 15) == 0) {
        float* dst = partials + (size_t)chunk * 16384 + slab * 64 + (t >> 4);
        dst[ 0] = s0;
        dst[16] = s1;
        dst[32] = s2;
        dst[48] = s3;
    }
}

// ---------------------------------------------------------------------------
// Kernel B: one block per (ps, b). Stages X-slab / wV in LDS, reduces the 8
// score partials into Ws while staging, softmaxes the 64 rows (4 thr/row),
// computes v with 4x4 register tiles, transposes via LDS, then weights @ v.
// LDS rows stride 68 floats: 16B-aligned, conflict-free for both patterns.
// ---------------------------------------------------------------------------
__global__ __launch_bounds__(256) void attn_out_kernel(
    const float* __restrict__ X, const float* __restrict__ wV,
    const float* __restrict__ partials, float* __restrict__ out)
{
    const int blk = blockIdx.x;   // 0..255
    const int ps  = blk >> 6;     // 0..3
    const int b   = blk & 63;     // 0..63
    const int t   = threadIdx.x;  // 0..255
    const int tc  = t >> 4;       // 0..15
    const int tf  = t & 15;       // 0..15

    __shared__ float Xs [64][68];   // X[b, ps, c, f0]
    __shared__ float wVs[64][68];   // wV[f1][f0]
    __shared__ float Ws [64][68];   // summed scores -> softmaxed weights [c][d]
    __shared__ float VsT[64][68];   // v transposed: [f1][c]

    const float4* xsrc = reinterpret_cast<const float4*>(X + (size_t)b * 16384 + ps * 4096);
    const float4* wsrc = reinterpret_cast<const float4*>(wV);
    const float4* psrc = reinterpret_cast<const float4*>(partials);
#pragma unroll
    for (int idx = t; idx < 1024; idx += 256) {
        int r = idx >> 4, jq = idx & 15, j = jq * 4;
        *reinterpret_cast<float4*>(&Xs [r][j]) = xsrc[idx];
        *reinterpret_cast<float4*>(&wVs[r][j]) = wsrc[idx];
        // sum the 8 chunk partials for (c=r, d=j..j+3)
        float4 s = make_float4(0.f, 0.f, 0.f, 0.f);
#pragma unroll
        for (int k = 0; k < 8; ++k) {
            float4 p = psrc[k * 4096 + (ps * 64 + r) * 16 + jq];
            s.x += p.x; s.y += p.y; s.z += p.z; s.w += p.w;
        }
        *reinterpret_cast<float4*>(&Ws [r][j]) = s;
    }
    __syncthreads();

    // v: acc[ci][fi] = sum_f0 Xs[4tc+ci][f0] * wVs[tf+16fi][f0]
    float acc[4][4] = {};
    for (int f0 = 0; f0 < 64; f0 += 4) {
        float4 xa[4], wv[4];
#pragma unroll
        for (int ci = 0; ci < 4; ++ci)
            xa[ci] = *reinterpret_cast<const float4*>(&Xs[4 * tc + ci][f0]);
#pragma unroll
        for (int fi = 0; fi < 4; ++fi)
            wv[fi] = *reinterpret_cast<const float4*>(&wVs[tf + 16 * fi][f0]);
#pragma unroll
        for (int ci = 0; ci < 4; ++ci)
#pragma unroll
            for (int fi = 0; fi < 4; ++fi)
                acc[ci][fi] += xa[ci].x * wv[fi].x + xa[ci].y * wv[fi].y
                             + xa[ci].z * wv[fi].z + xa[ci].w * wv[fi].w;
    }

    // softmax over d for each of the 64 rows of Ws; 4 threads per row
    {
        const int row = t >> 2, q = (t & 3) * 16;
        float e[16];
        float mx = -INFINITY;
#pragma unroll
        for (int i = 0; i < 16; ++i) mx = fmaxf(mx, Ws[row][q + i]);
        mx = fmaxf(mx, __shfl_xor(mx, 1, 64));
        mx = fmaxf(mx, __shfl_xor(mx, 2, 64));
        float sum = 0.f;
#pragma unroll
        for (int i = 0; i < 16; ++i) { e[i] = expf(Ws[row][q + i] - mx); sum += e[i]; }
        sum += __shfl_xor(sum, 1, 64);
        sum += __shfl_xor(sum, 2, 64);
        const float rinv = 1.0f / sum;
#pragma unroll
        for (int i = 0; i < 16; ++i) Ws[row][q + i] = e[i] * rinv;
    }

    // v -> LDS transposed
#pragma unroll
    for (int ci = 0; ci < 4; ++ci)
#pragma unroll
        for (int fi = 0; fi < 4; ++fi)
            VsT[tf + 16 * fi][4 * tc + ci] = acc[ci][fi];
    __syncthreads();

    // out: o[ci][fi] = sum_d Ws[4tc+ci][d] * VsT[tf+16fi][d]
    float o[4][4] = {};
    for (int d = 0; d < 64; d += 4) {
        float4 wa[4], va[4];
#pragma unroll
        for (int ci = 0; ci < 4; ++ci)
            wa[ci] = *reinterpret_cast<const float4*>(&Ws[4 * tc + ci][d]);
#pragma unroll
        for (int fi = 0; fi < 4; ++fi)
            va[fi] = *reinterpret_cast<const float4*>(&VsT[tf + 16 * fi][d]);
#pragma unroll
        for (int ci = 0; ci < 4; ++ci)
#pragma unroll
            for (int fi = 0; fi < 4; ++fi)
                o[ci][fi] += wa[ci].x * va[fi].x + wa[ci].y * va[fi].y
                           + wa[ci].z * va[fi].z + wa[ci].w * va[fi].w;
    }

    // out[c, b, ps*64 + f1],  c = 4tc+ci,  f1 = tf+16fi
#pragma unroll
    for (int ci = 0; ci < 4; ++ci) {
        const int c = 4 * tc + ci;
        float* orow = out + ((size_t)c * 64 + b) * 256 + ps * 64;
#pragma unroll
        for (int fi = 0; fi < 4; ++fi)
            orow[tf + 16 * fi] = o[ci][fi];
    }
}

extern "C" void kernel_launch(void* const* d_in, const int* in_sizes, int n_in,
                              void* d_out, int out_size, void* d_ws, size_t ws_size,
                              hipStream_t stream)
{
    const float* X    = (const float*)d_in[0];  // [64, 16384]
    const float* dbfc = (const float*)d_in[1];  // [2,2,64,64,64,64]
    const float* wV   = (const float*)d_in[2];  // [64, 64]
    float* out        = (float*)d_out;          // [64, 64, 256]
    float* partials   = (float*)d_ws;           // [8][256][64] = 512 KB scratch

    scores_partial_kernel<<<2048, 256, 0, stream>>>(dbfc, partials);
    attn_out_kernel<<<256, 256, 0, stream>>>(X, wV, partials, out);
}